// Round 1
// baseline (734.854 us; speedup 1.0000x reference)
//
#include <hip/hip_runtime.h>
#include <math.h>

#define B_ 256
#define T_ 512
#define D_ 300
#define U_ 64
#define C_ 45
#define N3 192   // 3*U

// ---------------------------------------------------------------------------
// Kernel 1: input projection  mx[m][j] = sum_k x[m][k] * w[k][j] + bias0[j]
// M = B*T = 131072 rows. grid 4096 x 192 threads, 32 rows per block.
// Thread j owns output column j; x tile staged in LDS, read as uniform b128
// broadcasts (1 per 4 FMAs); kernel columns loaded coalesced (L2-resident).
// ---------------------------------------------------------------------------
__global__ __launch_bounds__(192) void proj_kernel(
    const float* __restrict__ x,      // [M, 300]
    const float* __restrict__ w,      // [300, 192]
    const float* __restrict__ bias,   // [2, 192], row 0 = input bias
    float* __restrict__ mx)           // [M, 192]
{
    __shared__ float xl[32 * 300];    // 38.4 KB
    const int j  = threadIdx.x;       // 0..191
    const int m0 = blockIdx.x * 32;

    // stage 32 contiguous rows (9600 floats) as float4
    const float4* xg4 = (const float4*)(x + (size_t)m0 * 300);
    float4* xl4 = (float4*)xl;
    for (int f = j; f < 2400; f += 192) xl4[f] = xg4[f];
    __syncthreads();

    float acc[32];
    const float b0 = bias[j];
#pragma unroll
    for (int m = 0; m < 32; ++m) acc[m] = b0;

    const float* wc = w + j;
    for (int kq = 0; kq < 75; ++kq) {
        const int k0 = kq * 4;
        const float w0 = wc[(size_t)(k0 + 0) * 192];
        const float w1 = wc[(size_t)(k0 + 1) * 192];
        const float w2 = wc[(size_t)(k0 + 2) * 192];
        const float w3 = wc[(size_t)(k0 + 3) * 192];
#pragma unroll
        for (int m = 0; m < 32; ++m) {
            const float4 xv = ((const float4*)(xl + m * 300))[kq];
            acc[m] = fmaf(xv.x, w0, acc[m]);
            acc[m] = fmaf(xv.y, w1, acc[m]);
            acc[m] = fmaf(xv.z, w2, acc[m]);
            acc[m] = fmaf(xv.w, w3, acc[m]);
        }
    }
#pragma unroll
    for (int m = 0; m < 32; ++m)
        mx[(size_t)(m0 + m) * 192 + j] = acc[m];
}

// ---------------------------------------------------------------------------
// Kernel 2: the GRU scan. One block per batch element (256 blocks = 256 CUs),
// 192 threads = 3 waves = {z, r, hcand} sections. Thread j keeps recurrent
// kernel column j in 64 VGPRs. h broadcast via LDS (16 uniform b128 reads).
// 2 barriers per step. mx prefetched 3 steps ahead in rotating registers.
// ---------------------------------------------------------------------------
__global__ __launch_bounds__(192) void scan_kernel(
    const float* __restrict__ mx,    // [B, T, 192]
    const float* __restrict__ rk,    // [64, 192]
    const float* __restrict__ bias,  // [2, 192], row 1 = recurrent bias
    float* __restrict__ hs)          // [B, T, 64]
{
    __shared__ float hbuf[64];
    __shared__ float zbuf[64];
    __shared__ float rbuf[64];
    const int j = threadIdx.x;
    const int b = blockIdx.x;

    float Rv[64];
#pragma unroll
    for (int u = 0; u < 64; ++u) Rv[u] = rk[u * 192 + j];   // coalesced
    const float rb = bias[192 + j];

    if (j < 64) hbuf[j] = 0.f;
    __syncthreads();

    const float* mxb = mx + (size_t)b * T_ * 192 + j;
    float* hsb = hs + (size_t)b * T_ * 64;

    float c0 = mxb[0 * 192];
    float c1 = mxb[1 * 192];
    float c2 = mxb[2 * 192];

    for (int t = 0; t < T_; ++t) {
        int tp = t + 3; if (tp > T_ - 1) tp = T_ - 1;
        const float cn = mxb[(size_t)tp * 192];              // prefetch

        // mi_j = rec_bias_j + sum_u h[u] * R[u][j]  (4 independent chains)
        const float4* h4 = (const float4*)hbuf;
        float a0 = rb, a1 = 0.f, a2 = 0.f, a3 = 0.f;
#pragma unroll
        for (int g = 0; g < 16; ++g) {
            const float4 hv = h4[g];
            a0 = fmaf(hv.x, Rv[4 * g + 0], a0);
            a1 = fmaf(hv.y, Rv[4 * g + 1], a1);
            a2 = fmaf(hv.z, Rv[4 * g + 2], a2);
            a3 = fmaf(hv.w, Rv[4 * g + 3], a3);
        }
        const float mi  = (a0 + a1) + (a2 + a3);
        const float mxc = c0;

        if (j < 128) {   // waves 0,1: update & reset gates
            const float g = 1.f / (1.f + __expf(-(mxc + mi)));
            if (j < 64) zbuf[j] = g; else rbuf[j - 64] = g;
        }
        __syncthreads();
        if (j >= 128) { // wave 2: candidate + state update
            const int u = j - 128;
            const float r  = rbuf[u];
            const float hh = fmaxf(fmaf(r, mi, mxc), 0.f);   // relu(xh + r*rh)
            const float z  = zbuf[u];
            const float hn = z * hbuf[u] + (1.f - z) * hh;
            hbuf[u] = hn;
            hsb[(size_t)t * 64 + u] = hn;
        }
        __syncthreads();
        c0 = c1; c1 = c2; c2 = cn;
    }
}

// ---------------------------------------------------------------------------
// Kernel 3: logits = hs @ dense_w + dense_b, softmax over C=45.
// Wave-per-row; lane c holds dense_w column c in 64 VGPRs; h broadcast via
// per-wave LDS slice; softmax via 64-lane shfl_xor butterfly (pad -inf / 0).
// ---------------------------------------------------------------------------
__global__ __launch_bounds__(256) void head_kernel(
    const float* __restrict__ hs,   // [M, 64]
    const float* __restrict__ dw,   // [64, 45]
    const float* __restrict__ db,   // [45]
    float* __restrict__ out)        // [M, 45]
{
    __shared__ float hrow[4][64];
    const int lane = threadIdx.x & 63;
    const int wv   = threadIdx.x >> 6;

    float Wreg[64];
    float bj = 0.f;
    if (lane < C_) {
        bj = db[lane];
#pragma unroll
        for (int u = 0; u < 64; ++u) Wreg[u] = dw[u * C_ + lane];
    } else {
#pragma unroll
        for (int u = 0; u < 64; ++u) Wreg[u] = 0.f;
    }

    const int gw = blockIdx.x * 4 + wv;
    const int nw = gridDim.x * 4;
    const int M  = B_ * T_;
    for (int row = gw; row < M; row += nw) {
        const float h = hs[(size_t)row * 64 + lane];
        hrow[wv][lane] = h;
        __syncthreads();   // trip counts identical across waves (M % nw == 0)

        float acc = bj;
        const float4* h4 = (const float4*)hrow[wv];
#pragma unroll
        for (int g = 0; g < 16; ++g) {
            const float4 hv = h4[g];
            acc = fmaf(hv.x, Wreg[4 * g + 0], acc);
            acc = fmaf(hv.y, Wreg[4 * g + 1], acc);
            acc = fmaf(hv.z, Wreg[4 * g + 2], acc);
            acc = fmaf(hv.w, Wreg[4 * g + 3], acc);
        }

        float lg = (lane < C_) ? acc : -INFINITY;
        float mxv = lg;
#pragma unroll
        for (int s = 32; s; s >>= 1) mxv = fmaxf(mxv, __shfl_xor(mxv, s, 64));
        const float e = (lane < C_) ? __expf(lg - mxv) : 0.f;
        float ssum = e;
#pragma unroll
        for (int s = 32; s; s >>= 1) ssum += __shfl_xor(ssum, s, 64);
        if (lane < C_) out[(size_t)row * C_ + lane] = e / ssum;
        __syncthreads();
    }
}

// ---------------------------------------------------------------------------
extern "C" void kernel_launch(void* const* d_in, const int* in_sizes, int n_in,
                              void* d_out, int out_size, void* d_ws, size_t ws_size,
                              hipStream_t stream) {
    const float* x  = (const float*)d_in[0];
    const float* w  = (const float*)d_in[1];
    const float* rk = (const float*)d_in[2];
    const float* bs = (const float*)d_in[3];
    const float* dw = (const float*)d_in[4];
    const float* db = (const float*)d_in[5];
    float* out = (float*)d_out;

    float* mx = (float*)d_ws;                                     // 131072*192*4 = 100.66 MB
    float* hs = (float*)((char*)d_ws + (size_t)131072 * 192 * 4); // 131072*64*4  =  33.55 MB

    proj_kernel<<<4096, 192, 0, stream>>>(x, w, bs, mx);
    scan_kernel<<<256,  192, 0, stream>>>(mx, rk, bs, hs);
    head_kernel<<<2048, 256, 0, stream>>>(hs, dw, db, out);
}

// Round 2
// 728.277 us; speedup vs baseline: 1.0090x; 1.0090x over previous
//
#include <hip/hip_runtime.h>
#include <math.h>

#define B_ 256
#define T_ 512
#define D_ 300
#define U_ 64
#define C_ 45

// ---------------------------------------------------------------------------
// Kernel 1: input projection  mx[m][j] = sum_k x[m][k] * w[k][j] + bias0[j]
// M = B*T = 131072 rows. 4096 blocks x 192 threads. BM=32 rows, all 192 cols.
// Thread = (mg = tid&7 -> 4 rows, ng = tid>>3 -> 8 cols): 4x8 = 32 accs.
// x tile transposed in LDS ([k][m], conflict-free), w double-buffered in LDS
// chunks of BK=25. Per k: 1 ds_read_b128 (x) + 2 ds_read_b128 (w) -> 32 FMAs.
// ---------------------------------------------------------------------------
__global__ __launch_bounds__(192) void proj_kernel(
    const float* __restrict__ x,      // [M, 300]
    const float* __restrict__ w,      // [300, 192]
    const float* __restrict__ bias,   // [2, 192], row 0 = input bias
    float* __restrict__ mx)           // [M, 192]
{
    __shared__ float xt[300][32];     // 38.4 KB, transposed x tile
    __shared__ float wl[2][25][192];  // 38.4 KB, w chunk double buffer
    const int tid = threadIdx.x;
    const int m0  = blockIdx.x * 32;

    // ---- stage x tile transposed: thread covers row m = tid&31, kq strided ----
    {
        const int m   = tid & 31;
        const int kq0 = tid >> 5;                       // 0..5
        const float* xr = x + (size_t)(m0 + m) * 300;   // row base, 16B aligned
        for (int kq = kq0; kq < 75; kq += 6) {
            const float4 v = ((const float4*)xr)[kq];
            xt[kq * 4 + 0][m] = v.x;                    // lanes span m -> banks 0..31
            xt[kq * 4 + 1][m] = v.y;
            xt[kq * 4 + 2][m] = v.z;
            xt[kq * 4 + 3][m] = v.w;
        }
    }
    // ---- stage first w chunk (rows 0..24, contiguous copy) ----
    {
        const float4* wg = (const float4*)w;
        float4* wd = (float4*)&wl[0][0][0];
        for (int f = tid; f < 1200; f += 192) wd[f] = wg[f];
    }
    __syncthreads();

    const int mg = tid & 7;     // row group: rows mg*4 .. +4
    const int ng = tid >> 3;    // col group: cols ng*8 .. +8

    float acc[4][8];
    {
        const float4 b0 = *(const float4*)&bias[ng * 8];
        const float4 b1 = *(const float4*)&bias[ng * 8 + 4];
#pragma unroll
        for (int i = 0; i < 4; ++i) {
            acc[i][0] = b0.x; acc[i][1] = b0.y; acc[i][2] = b0.z; acc[i][3] = b0.w;
            acc[i][4] = b1.x; acc[i][5] = b1.y; acc[i][6] = b1.z; acc[i][7] = b1.w;
        }
    }

    float4 stage[7];
    for (int c = 0; c < 12; ++c) {
        // issue global loads for chunk c+1 (hidden under 800 FMAs below)
        if (c < 11) {
            const float4* wg = (const float4*)(w + (size_t)(c + 1) * 25 * 192);
#pragma unroll
            for (int i = 0; i < 6; ++i) stage[i] = wg[tid + i * 192];
            if (tid < 48) stage[6] = wg[tid + 1152];
        }
        // compute 25 k's from buffer c&1
        const int kb = c * 25;
        const float (*wb)[192] = wl[c & 1];
#pragma unroll 5
        for (int kk = 0; kk < 25; ++kk) {
            const float4 xv = *(const float4*)&xt[kb + kk][mg * 4];
            const float4 wa = *(const float4*)&wb[kk][ng * 8];
            const float4 wc = *(const float4*)&wb[kk][ng * 8 + 4];
            const float xs[4] = {xv.x, xv.y, xv.z, xv.w};
#pragma unroll
            for (int i = 0; i < 4; ++i) {
                acc[i][0] = fmaf(xs[i], wa.x, acc[i][0]);
                acc[i][1] = fmaf(xs[i], wa.y, acc[i][1]);
                acc[i][2] = fmaf(xs[i], wa.z, acc[i][2]);
                acc[i][3] = fmaf(xs[i], wa.w, acc[i][3]);
                acc[i][4] = fmaf(xs[i], wc.x, acc[i][4]);
                acc[i][5] = fmaf(xs[i], wc.y, acc[i][5]);
                acc[i][6] = fmaf(xs[i], wc.z, acc[i][6]);
                acc[i][7] = fmaf(xs[i], wc.w, acc[i][7]);
            }
        }
        // write staged chunk into the other buffer, one barrier per chunk
        if (c < 11) {
            float4* wd = (float4*)&wl[(c + 1) & 1][0][0];
#pragma unroll
            for (int i = 0; i < 6; ++i) wd[tid + i * 192] = stage[i];
            if (tid < 48) wd[tid + 1152] = stage[6];
        }
        __syncthreads();
    }

    // epilogue: store 4 rows x 8 cols
#pragma unroll
    for (int i = 0; i < 4; ++i) {
        float* outp = mx + (size_t)(m0 + mg * 4 + i) * 192 + ng * 8;
        float4 v0 = {acc[i][0], acc[i][1], acc[i][2], acc[i][3]};
        float4 v1 = {acc[i][4], acc[i][5], acc[i][6], acc[i][7]};
        ((float4*)outp)[0] = v0;
        ((float4*)outp)[1] = v1;
    }
}

// ---------------------------------------------------------------------------
// Kernel 2: the GRU scan (unchanged from round 1).
// ---------------------------------------------------------------------------
__global__ __launch_bounds__(192) void scan_kernel(
    const float* __restrict__ mx,    // [B, T, 192]
    const float* __restrict__ rk,    // [64, 192]
    const float* __restrict__ bias,  // [2, 192], row 1 = recurrent bias
    float* __restrict__ hs)          // [B, T, 64]
{
    __shared__ float hbuf[64];
    __shared__ float zbuf[64];
    __shared__ float rbuf[64];
    const int j = threadIdx.x;
    const int b = blockIdx.x;

    float Rv[64];
#pragma unroll
    for (int u = 0; u < 64; ++u) Rv[u] = rk[u * 192 + j];   // coalesced
    const float rb = bias[192 + j];

    if (j < 64) hbuf[j] = 0.f;
    __syncthreads();

    const float* mxb = mx + (size_t)b * T_ * 192 + j;
    float* hsb = hs + (size_t)b * T_ * 64;

    float c0 = mxb[0 * 192];
    float c1 = mxb[1 * 192];
    float c2 = mxb[2 * 192];

    for (int t = 0; t < T_; ++t) {
        int tp = t + 3; if (tp > T_ - 1) tp = T_ - 1;
        const float cn = mxb[(size_t)tp * 192];              // prefetch

        const float4* h4 = (const float4*)hbuf;
        float a0 = rb, a1 = 0.f, a2 = 0.f, a3 = 0.f;
#pragma unroll
        for (int g = 0; g < 16; ++g) {
            const float4 hv = h4[g];
            a0 = fmaf(hv.x, Rv[4 * g + 0], a0);
            a1 = fmaf(hv.y, Rv[4 * g + 1], a1);
            a2 = fmaf(hv.z, Rv[4 * g + 2], a2);
            a3 = fmaf(hv.w, Rv[4 * g + 3], a3);
        }
        const float mi  = (a0 + a1) + (a2 + a3);
        const float mxc = c0;

        if (j < 128) {   // waves 0,1: update & reset gates
            const float g = 1.f / (1.f + __expf(-(mxc + mi)));
            if (j < 64) zbuf[j] = g; else rbuf[j - 64] = g;
        }
        __syncthreads();
        if (j >= 128) { // wave 2: candidate + state update
            const int u = j - 128;
            const float r  = rbuf[u];
            const float hh = fmaxf(fmaf(r, mi, mxc), 0.f);   // relu(xh + r*rh)
            const float z  = zbuf[u];
            const float hn = z * hbuf[u] + (1.f - z) * hh;
            hbuf[u] = hn;
            hsb[(size_t)t * 64 + u] = hn;
        }
        __syncthreads();
        c0 = c1; c1 = c2; c2 = cn;
    }
}

// ---------------------------------------------------------------------------
// Kernel 3: logits + softmax (unchanged from round 1).
// ---------------------------------------------------------------------------
__global__ __launch_bounds__(256) void head_kernel(
    const float* __restrict__ hs,   // [M, 64]
    const float* __restrict__ dw,   // [64, 45]
    const float* __restrict__ db,   // [45]
    float* __restrict__ out)        // [M, 45]
{
    __shared__ float hrow[4][64];
    const int lane = threadIdx.x & 63;
    const int wv   = threadIdx.x >> 6;

    float Wreg[64];
    float bj = 0.f;
    if (lane < C_) {
        bj = db[lane];
#pragma unroll
        for (int u = 0; u < 64; ++u) Wreg[u] = dw[u * C_ + lane];
    } else {
#pragma unroll
        for (int u = 0; u < 64; ++u) Wreg[u] = 0.f;
    }

    const int gw = blockIdx.x * 4 + wv;
    const int nw = gridDim.x * 4;
    const int M  = B_ * T_;
    for (int row = gw; row < M; row += nw) {
        const float h = hs[(size_t)row * 64 + lane];
        hrow[wv][lane] = h;
        __syncthreads();

        float acc = bj;
        const float4* h4 = (const float4*)hrow[wv];
#pragma unroll
        for (int g = 0; g < 16; ++g) {
            const float4 hv = h4[g];
            acc = fmaf(hv.x, Wreg[4 * g + 0], acc);
            acc = fmaf(hv.y, Wreg[4 * g + 1], acc);
            acc = fmaf(hv.z, Wreg[4 * g + 2], acc);
            acc = fmaf(hv.w, Wreg[4 * g + 3], acc);
        }

        float lg = (lane < C_) ? acc : -INFINITY;
        float mxv = lg;
#pragma unroll
        for (int s = 32; s; s >>= 1) mxv = fmaxf(mxv, __shfl_xor(mxv, s, 64));
        const float e = (lane < C_) ? __expf(lg - mxv) : 0.f;
        float ssum = e;
#pragma unroll
        for (int s = 32; s; s >>= 1) ssum += __shfl_xor(ssum, s, 64);
        if (lane < C_) out[(size_t)row * C_ + lane] = e / ssum;
        __syncthreads();
    }
}

// ---------------------------------------------------------------------------
extern "C" void kernel_launch(void* const* d_in, const int* in_sizes, int n_in,
                              void* d_out, int out_size, void* d_ws, size_t ws_size,
                              hipStream_t stream) {
    const float* x  = (const float*)d_in[0];
    const float* w  = (const float*)d_in[1];
    const float* rk = (const float*)d_in[2];
    const float* bs = (const float*)d_in[3];
    const float* dw = (const float*)d_in[4];
    const float* db = (const float*)d_in[5];
    float* out = (float*)d_out;

    float* mx = (float*)d_ws;                                     // 100.66 MB
    float* hs = (float*)((char*)d_ws + (size_t)131072 * 192 * 4); //  33.55 MB

    proj_kernel<<<4096, 192, 0, stream>>>(x, w, bs, mx);
    scan_kernel<<<256,  192, 0, stream>>>(mx, rk, bs, hs);
    head_kernel<<<2048, 256, 0, stream>>>(hs, dw, db, out);
}

// Round 3
// 460.088 us; speedup vs baseline: 1.5972x; 1.5829x over previous
//
#include <hip/hip_runtime.h>
#include <math.h>

#define B_ 256
#define T_ 512
#define D_ 300
#define U_ 64
#define C_ 45

typedef _Float16 half_t;
typedef __attribute__((ext_vector_type(8))) _Float16 f16x8;
typedef __attribute__((ext_vector_type(4))) float f32x4;

// K padded 300 -> 320 (10 MFMA K-steps of 32). 12 N-tiles of 16 cols (192).
#define KSTEPS 10
#define NTILES 12

// ---------------------------------------------------------------------------
// prep: build fragment-ready transposed w in fp16 hi/lo split.
// wt[((ks*12 + nt)*64 + lane)*8 + e] = w[k][col],  k = ks*32 + (lane>>4)*8 + e,
// col = nt*16 + (lane&15); zero for k >= 300.  7680 threads, one frag-lane each.
// ---------------------------------------------------------------------------
__global__ __launch_bounds__(256) void prep_kernel(
    const float* __restrict__ w,     // [300, 192]
    half_t* __restrict__ wt_hi,      // [7680*8]
    half_t* __restrict__ wt_lo)      // [7680*8]
{
    const int idx = blockIdx.x * 256 + threadIdx.x;
    if (idx >= KSTEPS * NTILES * 64) return;
    const int l  = idx & 63;
    const int nt = (idx >> 6) % NTILES;
    const int ks = idx / (64 * NTILES);
    const int col   = nt * 16 + (l & 15);
    const int kbase = ks * 32 + (l >> 4) * 8;

    half_t hi[8], lo[8];
#pragma unroll
    for (int e = 0; e < 8; ++e) {
        const int k = kbase + e;
        const float v = (k < D_) ? w[(size_t)k * 192 + col] : 0.f;
        const half_t h = (half_t)v;
        hi[e] = h;
        lo[e] = (half_t)(v - (float)h);
    }
    *(f16x8*)(wt_hi + (size_t)idx * 8) = *(const f16x8*)hi;
    *(f16x8*)(wt_lo + (size_t)idx * 8) = *(const f16x8*)lo;
}

// ---------------------------------------------------------------------------
// Kernel 1: input projection via MFMA, fp16 hi/lo split (fp32-equivalent).
// 2048 blocks x 256 threads. BM=64 (4 M-tiles), BN=192 (wave wv owns 3
// N-tiles = cols wv*48..wv*48+48). No LDS: A-frags straight from global x
// (converted in regs), B-frags from frag-ready wt_hi/wt_lo (L2-resident).
// ---------------------------------------------------------------------------
__global__ __launch_bounds__(256, 4) void proj_kernel(
    const float*  __restrict__ x,      // [M, 300]
    const half_t* __restrict__ wt_hi,
    const half_t* __restrict__ wt_lo,
    const float*  __restrict__ bias,   // [2, 192], row 0 = input bias
    float* __restrict__ mx)            // [M, 192]
{
    const int tid  = threadIdx.x;
    const int l    = tid & 63;
    const int wv   = tid >> 6;          // 0..3
    const int lrow = l & 15;
    const int g    = l >> 4;            // 0..3 (k-group)
    const int m0   = blockIdx.x * 64;

    f32x4 acc[4][3];
#pragma unroll
    for (int ni = 0; ni < 3; ++ni) {
        const float b = bias[wv * 48 + ni * 16 + lrow];
        const f32x4 bv = {b, b, b, b};
#pragma unroll
        for (int mi = 0; mi < 4; ++mi) acc[mi][ni] = bv;
    }

    for (int ks = 0; ks < KSTEPS; ++ks) {
        // B fragments for this wave's 3 N-tiles (coalesced dwordx4 from L2)
        f16x8 bhi[3], blo[3];
#pragma unroll
        for (int ni = 0; ni < 3; ++ni) {
            const size_t off = ((size_t)(ks * NTILES + wv * 3 + ni) * 64 + l) * 8;
            bhi[ni] = *(const f16x8*)(wt_hi + off);
            blo[ni] = *(const f16x8*)(wt_lo + off);
        }
#pragma unroll
        for (int mi = 0; mi < 4; ++mi) {
            const float* xr = x + (size_t)(m0 + mi * 16 + lrow) * D_ + ks * 32 + g * 8;
            float xv[8];
            if (ks < 9) {
                const float4 v0 = ((const float4*)xr)[0];
                const float4 v1 = ((const float4*)xr)[1];
                xv[0] = v0.x; xv[1] = v0.y; xv[2] = v0.z; xv[3] = v0.w;
                xv[4] = v1.x; xv[5] = v1.y; xv[6] = v1.z; xv[7] = v1.w;
            } else {
                const int kb = 288 + g * 8;   // predicated tail (k in [288,320))
#pragma unroll
                for (int e = 0; e < 8; ++e) xv[e] = (kb + e < D_) ? xr[e] : 0.f;
            }
            f16x8 ahi, alo;
#pragma unroll
            for (int e = 0; e < 8; ++e) {
                const half_t h = (half_t)xv[e];
                ahi[e] = h;
                alo[e] = (half_t)(xv[e] - (float)h);
            }
#pragma unroll
            for (int ni = 0; ni < 3; ++ni) {
                acc[mi][ni] = __builtin_amdgcn_mfma_f32_16x16x32_f16(ahi, bhi[ni], acc[mi][ni], 0, 0, 0);
                acc[mi][ni] = __builtin_amdgcn_mfma_f32_16x16x32_f16(alo, bhi[ni], acc[mi][ni], 0, 0, 0);
                acc[mi][ni] = __builtin_amdgcn_mfma_f32_16x16x32_f16(ahi, blo[ni], acc[mi][ni], 0, 0, 0);
            }
        }
    }

    // epilogue: D-frag (col = l&15, row = 4*(l>>4)+r) -> mx
#pragma unroll
    for (int mi = 0; mi < 4; ++mi) {
        const int rbase = m0 + mi * 16 + g * 4;
#pragma unroll
        for (int ni = 0; ni < 3; ++ni) {
            const int col = wv * 48 + ni * 16 + lrow;
#pragma unroll
            for (int r = 0; r < 4; ++r)
                mx[(size_t)(rbase + r) * 192 + col] = acc[mi][ni][r];
        }
    }
}

// ---------------------------------------------------------------------------
// Kernel 2: the GRU scan (unchanged from round 1).
// ---------------------------------------------------------------------------
__global__ __launch_bounds__(192) void scan_kernel(
    const float* __restrict__ mx,    // [B, T, 192]
    const float* __restrict__ rk,    // [64, 192]
    const float* __restrict__ bias,  // [2, 192], row 1 = recurrent bias
    float* __restrict__ hs)          // [B, T, 64]
{
    __shared__ float hbuf[64];
    __shared__ float zbuf[64];
    __shared__ float rbuf[64];
    const int j = threadIdx.x;
    const int b = blockIdx.x;

    float Rv[64];
#pragma unroll
    for (int u = 0; u < 64; ++u) Rv[u] = rk[u * 192 + j];   // coalesced
    const float rb = bias[192 + j];

    if (j < 64) hbuf[j] = 0.f;
    __syncthreads();

    const float* mxb = mx + (size_t)b * T_ * 192 + j;
    float* hsb = hs + (size_t)b * T_ * 64;

    float c0 = mxb[0 * 192];
    float c1 = mxb[1 * 192];
    float c2 = mxb[2 * 192];

    for (int t = 0; t < T_; ++t) {
        int tp = t + 3; if (tp > T_ - 1) tp = T_ - 1;
        const float cn = mxb[(size_t)tp * 192];              // prefetch

        const float4* h4 = (const float4*)hbuf;
        float a0 = rb, a1 = 0.f, a2 = 0.f, a3 = 0.f;
#pragma unroll
        for (int g = 0; g < 16; ++g) {
            const float4 hv = h4[g];
            a0 = fmaf(hv.x, Rv[4 * g + 0], a0);
            a1 = fmaf(hv.y, Rv[4 * g + 1], a1);
            a2 = fmaf(hv.z, Rv[4 * g + 2], a2);
            a3 = fmaf(hv.w, Rv[4 * g + 3], a3);
        }
        const float mi  = (a0 + a1) + (a2 + a3);
        const float mxc = c0;

        if (j < 128) {   // waves 0,1: update & reset gates
            const float g = 1.f / (1.f + __expf(-(mxc + mi)));
            if (j < 64) zbuf[j] = g; else rbuf[j - 64] = g;
        }
        __syncthreads();
        if (j >= 128) { // wave 2: candidate + state update
            const int u = j - 128;
            const float r  = rbuf[u];
            const float hh = fmaxf(fmaf(r, mi, mxc), 0.f);   // relu(xh + r*rh)
            const float z  = zbuf[u];
            const float hn = z * hbuf[u] + (1.f - z) * hh;
            hbuf[u] = hn;
            hsb[(size_t)t * 64 + u] = hn;
        }
        __syncthreads();
        c0 = c1; c1 = c2; c2 = cn;
    }
}

// ---------------------------------------------------------------------------
// Kernel 3: logits + softmax (unchanged from round 1).
// ---------------------------------------------------------------------------
__global__ __launch_bounds__(256) void head_kernel(
    const float* __restrict__ hs,   // [M, 64]
    const float* __restrict__ dw,   // [64, 45]
    const float* __restrict__ db,   // [45]
    float* __restrict__ out)        // [M, 45]
{
    __shared__ float hrow[4][64];
    const int lane = threadIdx.x & 63;
    const int wv   = threadIdx.x >> 6;

    float Wreg[64];
    float bj = 0.f;
    if (lane < C_) {
        bj = db[lane];
#pragma unroll
        for (int u = 0; u < 64; ++u) Wreg[u] = dw[u * C_ + lane];
    } else {
#pragma unroll
        for (int u = 0; u < 64; ++u) Wreg[u] = 0.f;
    }

    const int gw = blockIdx.x * 4 + wv;
    const int nw = gridDim.x * 4;
    const int M  = B_ * T_;
    for (int row = gw; row < M; row += nw) {
        const float h = hs[(size_t)row * 64 + lane];
        hrow[wv][lane] = h;
        __syncthreads();

        float acc = bj;
        const float4* h4 = (const float4*)hrow[wv];
#pragma unroll
        for (int g = 0; g < 16; ++g) {
            const float4 hv = h4[g];
            acc = fmaf(hv.x, Wreg[4 * g + 0], acc);
            acc = fmaf(hv.y, Wreg[4 * g + 1], acc);
            acc = fmaf(hv.z, Wreg[4 * g + 2], acc);
            acc = fmaf(hv.w, Wreg[4 * g + 3], acc);
        }

        float lg = (lane < C_) ? acc : -INFINITY;
        float mxv = lg;
#pragma unroll
        for (int s = 32; s; s >>= 1) mxv = fmaxf(mxv, __shfl_xor(mxv, s, 64));
        const float e = (lane < C_) ? __expf(lg - mxv) : 0.f;
        float ssum = e;
#pragma unroll
        for (int s = 32; s; s >>= 1) ssum += __shfl_xor(ssum, s, 64);
        if (lane < C_) out[(size_t)row * C_ + lane] = e / ssum;
        __syncthreads();
    }
}

// ---------------------------------------------------------------------------
extern "C" void kernel_launch(void* const* d_in, const int* in_sizes, int n_in,
                              void* d_out, int out_size, void* d_ws, size_t ws_size,
                              hipStream_t stream) {
    const float* x  = (const float*)d_in[0];
    const float* w  = (const float*)d_in[1];
    const float* rk = (const float*)d_in[2];
    const float* bs = (const float*)d_in[3];
    const float* dw = (const float*)d_in[4];
    const float* db = (const float*)d_in[5];
    float* out = (float*)d_out;

    char* ws = (char*)d_ws;
    float*  mx    = (float*)ws;                                  // 100.66 MB
    float*  hs    = (float*)(ws + (size_t)131072 * 192 * 4);     //  33.55 MB
    half_t* wt_hi = (half_t*)(ws + (size_t)131072 * 256 * 4);    // 122,880 B
    half_t* wt_lo = wt_hi + (size_t)KSTEPS * NTILES * 64 * 8;    // 122,880 B

    prep_kernel<<<30,   256, 0, stream>>>(w, wt_hi, wt_lo);
    proj_kernel<<<2048, 256, 0, stream>>>(x, wt_hi, wt_lo, bs, mx);
    scan_kernel<<<256,  192, 0, stream>>>(mx, rk, bs, hs);
    head_kernel<<<2048, 256, 0, stream>>>(hs, dw, db, out);
}

// Round 4
// 392.242 us; speedup vs baseline: 1.8735x; 1.1730x over previous
//
#include <hip/hip_runtime.h>
#include <math.h>

#define B_ 256
#define T_ 512
#define D_ 300
#define U_ 64
#define C_ 45

typedef _Float16 half_t;
typedef __attribute__((ext_vector_type(8))) _Float16 f16x8;
typedef __attribute__((ext_vector_type(4))) float f32x4;
typedef __attribute__((ext_vector_type(2))) float f32x2;

// K padded 300 -> 320 (10 MFMA K-steps of 32). 12 N-tiles of 16 cols (192).
#define KSTEPS 10
#define NTILES 12

#if __has_builtin(__builtin_elementwise_fma)
#define FMA2(a, b, c) __builtin_elementwise_fma((a), (b), (c))
#else
static __device__ inline f32x2 FMA2(f32x2 a, f32x2 b, f32x2 c) {
    f32x2 r; r.x = fmaf(a.x, b.x, c.x); r.y = fmaf(a.y, b.y, c.y); return r;
}
#endif

#if __has_builtin(__builtin_amdgcn_rcpf)
#define FRCP(x) __builtin_amdgcn_rcpf(x)
#else
#define FRCP(x) (1.0f / (x))
#endif

// ---------------------------------------------------------------------------
// prep: build fragment-ready transposed w in fp16 hi/lo split (unchanged).
// ---------------------------------------------------------------------------
__global__ __launch_bounds__(256) void prep_kernel(
    const float* __restrict__ w,     // [300, 192]
    half_t* __restrict__ wt_hi,      // [7680*8]
    half_t* __restrict__ wt_lo)      // [7680*8]
{
    const int idx = blockIdx.x * 256 + threadIdx.x;
    if (idx >= KSTEPS * NTILES * 64) return;
    const int l  = idx & 63;
    const int nt = (idx >> 6) % NTILES;
    const int ks = idx / (64 * NTILES);
    const int col   = nt * 16 + (l & 15);
    const int kbase = ks * 32 + (l >> 4) * 8;

    half_t hi[8], lo[8];
#pragma unroll
    for (int e = 0; e < 8; ++e) {
        const int k = kbase + e;
        const float v = (k < D_) ? w[(size_t)k * 192 + col] : 0.f;
        const half_t h = (half_t)v;
        hi[e] = h;
        lo[e] = (half_t)(v - (float)h);
    }
    *(f16x8*)(wt_hi + (size_t)idx * 8) = *(const f16x8*)hi;
    *(f16x8*)(wt_lo + (size_t)idx * 8) = *(const f16x8*)lo;
}

// ---------------------------------------------------------------------------
// Kernel 1: input projection via MFMA, fp16 hi/lo split (unchanged from R3).
// ---------------------------------------------------------------------------
__global__ __launch_bounds__(256, 4) void proj_kernel(
    const float*  __restrict__ x,      // [M, 300]
    const half_t* __restrict__ wt_hi,
    const half_t* __restrict__ wt_lo,
    const float*  __restrict__ bias,   // [2, 192], row 0 = input bias
    float* __restrict__ mx)            // [M, 192]
{
    const int tid  = threadIdx.x;
    const int l    = tid & 63;
    const int wv   = tid >> 6;          // 0..3
    const int lrow = l & 15;
    const int g    = l >> 4;            // 0..3 (k-group)
    const int m0   = blockIdx.x * 64;

    f32x4 acc[4][3];
#pragma unroll
    for (int ni = 0; ni < 3; ++ni) {
        const float b = bias[wv * 48 + ni * 16 + lrow];
        const f32x4 bv = {b, b, b, b};
#pragma unroll
        for (int mi = 0; mi < 4; ++mi) acc[mi][ni] = bv;
    }

    for (int ks = 0; ks < KSTEPS; ++ks) {
        f16x8 bhi[3], blo[3];
#pragma unroll
        for (int ni = 0; ni < 3; ++ni) {
            const size_t off = ((size_t)(ks * NTILES + wv * 3 + ni) * 64 + l) * 8;
            bhi[ni] = *(const f16x8*)(wt_hi + off);
            blo[ni] = *(const f16x8*)(wt_lo + off);
        }
#pragma unroll
        for (int mi = 0; mi < 4; ++mi) {
            const float* xr = x + (size_t)(m0 + mi * 16 + lrow) * D_ + ks * 32 + g * 8;
            float xv[8];
            if (ks < 9) {
                const float4 v0 = ((const float4*)xr)[0];
                const float4 v1 = ((const float4*)xr)[1];
                xv[0] = v0.x; xv[1] = v0.y; xv[2] = v0.z; xv[3] = v0.w;
                xv[4] = v1.x; xv[5] = v1.y; xv[6] = v1.z; xv[7] = v1.w;
            } else {
                const int kb = 288 + g * 8;   // predicated tail (k in [288,320))
#pragma unroll
                for (int e = 0; e < 8; ++e) xv[e] = (kb + e < D_) ? xr[e] : 0.f;
            }
            f16x8 ahi, alo;
#pragma unroll
            for (int e = 0; e < 8; ++e) {
                const half_t h = (half_t)xv[e];
                ahi[e] = h;
                alo[e] = (half_t)(xv[e] - (float)h);
            }
#pragma unroll
            for (int ni = 0; ni < 3; ++ni) {
                acc[mi][ni] = __builtin_amdgcn_mfma_f32_16x16x32_f16(ahi, bhi[ni], acc[mi][ni], 0, 0, 0);
                acc[mi][ni] = __builtin_amdgcn_mfma_f32_16x16x32_f16(alo, bhi[ni], acc[mi][ni], 0, 0, 0);
                acc[mi][ni] = __builtin_amdgcn_mfma_f32_16x16x32_f16(ahi, blo[ni], acc[mi][ni], 0, 0, 0);
            }
        }
    }

#pragma unroll
    for (int mi = 0; mi < 4; ++mi) {
        const int rbase = m0 + mi * 16 + g * 4;
#pragma unroll
        for (int ni = 0; ni < 3; ++ni) {
            const int col = wv * 48 + ni * 16 + lrow;
#pragma unroll
            for (int r = 0; r < 4; ++r)
                mx[(size_t)(rbase + r) * 192 + col] = acc[mi][ni][r];
        }
    }
}

// ---------------------------------------------------------------------------
// Kernel 2: GRU scan — single wave per batch element, zero barriers.
// 256 blocks x 64 threads. Lane j owns gate columns (j, 64+j, 128+j); the
// recurrent kernel lives in 192 VGPRs as f32x2 pairs (v_pk_fma_f32).
// h broadcast via wave-private LDS: 1 ds_write_b32 + 16 uniform ds_read_b128
// per step, ordered by lgkmcnt only (single wave -> no s_barrier).
// mx prefetched 3 steps ahead (3 coalesced dword loads/step).
// ---------------------------------------------------------------------------
__global__ __launch_bounds__(64, 1) void scan_kernel(
    const float* __restrict__ mx,    // [B, T, 192]
    const float* __restrict__ rk,    // [64, 192]
    const float* __restrict__ bias,  // [2, 192], row 1 = recurrent bias
    float* __restrict__ hs)          // [B, T, 64]
{
    __shared__ float hbuf[64];
    const int j = threadIdx.x;       // 0..63
    const int b = blockIdx.x;

    // recurrent kernel columns j / 64+j / 128+j as 32 f32x2 pairs each
    f32x2 Rz[32], Rr[32], Rh[32];
#pragma unroll
    for (int p = 0; p < 32; ++p) {
        Rz[p] = f32x2{rk[(size_t)(2 * p) * 192 + j],       rk[(size_t)(2 * p + 1) * 192 + j]};
        Rr[p] = f32x2{rk[(size_t)(2 * p) * 192 + 64 + j],  rk[(size_t)(2 * p + 1) * 192 + 64 + j]};
        Rh[p] = f32x2{rk[(size_t)(2 * p) * 192 + 128 + j], rk[(size_t)(2 * p + 1) * 192 + 128 + j]};
    }
    const float rbz = bias[192 + j];
    const float rbr = bias[192 + 64 + j];
    const float rbh = bias[192 + 128 + j];

    hbuf[j] = 0.f;
    float hj = 0.f;

    const float* mxb = mx + (size_t)b * T_ * 192 + j;
    float* hsb = hs + (size_t)b * T_ * 64 + j;

    // prefetch queue, depth 3
    float z0 = mxb[0],       r0 = mxb[64],        q0 = mxb[128];
    float z1 = mxb[192],     r1 = mxb[192 + 64],  q1 = mxb[192 + 128];
    float z2 = mxb[384],     r2 = mxb[384 + 64],  q2 = mxb[384 + 128];

    for (int t = 0; t < T_; ++t) {
        const int tp = (t + 3 < T_) ? (t + 3) : (T_ - 1);
        const float* pf = mxb + (size_t)tp * 192;
        const float zn = pf[0], rn = pf[64], qn = pf[128];

        // mi = h . R  (three 64-deep dot products, 96 pk-FMA, 6 chains)
        const float4* h4p = (const float4*)hbuf;
        f32x2 az0 = {rbz, 0.f}, az1 = {0.f, 0.f};
        f32x2 ar0 = {rbr, 0.f}, ar1 = {0.f, 0.f};
        f32x2 ah0 = {rbh, 0.f}, ah1 = {0.f, 0.f};
#pragma unroll
        for (int q = 0; q < 16; ++q) {
            const float4 hv = h4p[q];
            const f32x2 hA = {hv.x, hv.y};
            const f32x2 hB = {hv.z, hv.w};
            az0 = FMA2(hA, Rz[2 * q], az0);
            az1 = FMA2(hB, Rz[2 * q + 1], az1);
            ar0 = FMA2(hA, Rr[2 * q], ar0);
            ar1 = FMA2(hB, Rr[2 * q + 1], ar1);
            ah0 = FMA2(hA, Rh[2 * q], ah0);
            ah1 = FMA2(hB, Rh[2 * q + 1], ah1);
        }
        const f32x2 az = az0 + az1;
        const f32x2 ar = ar0 + ar1;
        const f32x2 ah = ah0 + ah1;
        const float miz = az.x + az.y;
        const float mir = ar.x + ar.y;
        const float mih = ah.x + ah.y;

        const float zg = FRCP(1.f + __expf(-(z0 + miz)));   // update gate
        const float rg = FRCP(1.f + __expf(-(r0 + mir)));   // reset gate
        const float hh = fmaxf(fmaf(rg, mih, q0), 0.f);     // relu candidate
        const float hn = fmaf(zg, hj - hh, hh);             // z*h + (1-z)*hh

        hbuf[j] = hn;
        hj = hn;
        hsb[(size_t)t * 64] = hn;

        z0 = z1; z1 = z2; z2 = zn;
        r0 = r1; r1 = r2; r2 = rn;
        q0 = q1; q1 = q2; q2 = qn;
    }
}

// ---------------------------------------------------------------------------
// Kernel 3: logits + softmax (unchanged).
// ---------------------------------------------------------------------------
__global__ __launch_bounds__(256) void head_kernel(
    const float* __restrict__ hs,   // [M, 64]
    const float* __restrict__ dw,   // [64, 45]
    const float* __restrict__ db,   // [45]
    float* __restrict__ out)        // [M, 45]
{
    __shared__ float hrow[4][64];
    const int lane = threadIdx.x & 63;
    const int wv   = threadIdx.x >> 6;

    float Wreg[64];
    float bj = 0.f;
    if (lane < C_) {
        bj = db[lane];
#pragma unroll
        for (int u = 0; u < 64; ++u) Wreg[u] = dw[u * C_ + lane];
    } else {
#pragma unroll
        for (int u = 0; u < 64; ++u) Wreg[u] = 0.f;
    }

    const int gw = blockIdx.x * 4 + wv;
    const int nw = gridDim.x * 4;
    const int M  = B_ * T_;
    for (int row = gw; row < M; row += nw) {
        const float h = hs[(size_t)row * 64 + lane];
        hrow[wv][lane] = h;
        __syncthreads();

        float acc = bj;
        const float4* h4 = (const float4*)hrow[wv];
#pragma unroll
        for (int g = 0; g < 16; ++g) {
            const float4 hv = h4[g];
            acc = fmaf(hv.x, Wreg[4 * g + 0], acc);
            acc = fmaf(hv.y, Wreg[4 * g + 1], acc);
            acc = fmaf(hv.z, Wreg[4 * g + 2], acc);
            acc = fmaf(hv.w, Wreg[4 * g + 3], acc);
        }

        float lg = (lane < C_) ? acc : -INFINITY;
        float mxv = lg;
#pragma unroll
        for (int s = 32; s; s >>= 1) mxv = fmaxf(mxv, __shfl_xor(mxv, s, 64));
        const float e = (lane < C_) ? __expf(lg - mxv) : 0.f;
        float ssum = e;
#pragma unroll
        for (int s = 32; s; s >>= 1) ssum += __shfl_xor(ssum, s, 64);
        if (lane < C_) out[(size_t)row * C_ + lane] = e / ssum;
        __syncthreads();
    }
}

// ---------------------------------------------------------------------------
extern "C" void kernel_launch(void* const* d_in, const int* in_sizes, int n_in,
                              void* d_out, int out_size, void* d_ws, size_t ws_size,
                              hipStream_t stream) {
    const float* x  = (const float*)d_in[0];
    const float* w  = (const float*)d_in[1];
    const float* rk = (const float*)d_in[2];
    const float* bs = (const float*)d_in[3];
    const float* dw = (const float*)d_in[4];
    const float* db = (const float*)d_in[5];
    float* out = (float*)d_out;

    char* ws = (char*)d_ws;
    float*  mx    = (float*)ws;                                  // 100.66 MB
    float*  hs    = (float*)(ws + (size_t)131072 * 192 * 4);     //  33.55 MB
    half_t* wt_hi = (half_t*)(ws + (size_t)131072 * 256 * 4);    // 122,880 B
    half_t* wt_lo = wt_hi + (size_t)KSTEPS * NTILES * 64 * 8;    // 122,880 B

    prep_kernel<<<30,   256, 0, stream>>>(w, wt_hi, wt_lo);
    proj_kernel<<<2048, 256, 0, stream>>>(x, wt_hi, wt_lo, bs, mx);
    scan_kernel<<<256,  64,  0, stream>>>(mx, rk, bs, hs);
    head_kernel<<<2048, 256, 0, stream>>>(hs, dw, db, out);
}

// Round 5
// 328.854 us; speedup vs baseline: 2.2346x; 1.1928x over previous
//
#include <hip/hip_runtime.h>
#include <math.h>

#define B_ 256
#define T_ 512
#define D_ 300
#define U_ 64
#define C_ 45

typedef _Float16 half_t;
typedef __attribute__((ext_vector_type(2))) _Float16 f16x2;
typedef __attribute__((ext_vector_type(8))) _Float16 f16x8;
typedef __attribute__((ext_vector_type(4))) float f32x4;

// K padded 300 -> 320 (10 MFMA K-steps of 32). 12 N-tiles of 16 cols (192).
#define KSTEPS 10
#define NTILES 12

#if __has_builtin(__builtin_amdgcn_rcpf)
#define FRCP(x) __builtin_amdgcn_rcpf(x)
#else
#define FRCP(x) (1.0f / (x))
#endif

static __device__ inline float fdot2_(f16x2 a, f16x2 b, float c) {
#if __has_builtin(__builtin_amdgcn_fdot2)
    return __builtin_amdgcn_fdot2(a, b, c, false);   // v_dot2_f32_f16
#else
    return fmaf((float)a.x, (float)b.x, fmaf((float)a.y, (float)b.y, c));
#endif
}

// ---------------------------------------------------------------------------
// prep: build fragment-ready transposed w in fp16 hi/lo split (unchanged).
// ---------------------------------------------------------------------------
__global__ __launch_bounds__(256) void prep_kernel(
    const float* __restrict__ w,     // [300, 192]
    half_t* __restrict__ wt_hi,      // [7680*8]
    half_t* __restrict__ wt_lo)      // [7680*8]
{
    const int idx = blockIdx.x * 256 + threadIdx.x;
    if (idx >= KSTEPS * NTILES * 64) return;
    const int l  = idx & 63;
    const int nt = (idx >> 6) % NTILES;
    const int ks = idx / (64 * NTILES);
    const int col   = nt * 16 + (l & 15);
    const int kbase = ks * 32 + (l >> 4) * 8;

    half_t hi[8], lo[8];
#pragma unroll
    for (int e = 0; e < 8; ++e) {
        const int k = kbase + e;
        const float v = (k < D_) ? w[(size_t)k * 192 + col] : 0.f;
        const half_t h = (half_t)v;
        hi[e] = h;
        lo[e] = (half_t)(v - (float)h);
    }
    *(f16x8*)(wt_hi + (size_t)idx * 8) = *(const f16x8*)hi;
    *(f16x8*)(wt_lo + (size_t)idx * 8) = *(const f16x8*)lo;
}

// ---------------------------------------------------------------------------
// Kernel 1: input projection via MFMA, fp16 hi/lo split (unchanged from R3).
// ---------------------------------------------------------------------------
__global__ __launch_bounds__(256, 4) void proj_kernel(
    const float*  __restrict__ x,      // [M, 300]
    const half_t* __restrict__ wt_hi,
    const half_t* __restrict__ wt_lo,
    const float*  __restrict__ bias,   // [2, 192], row 0 = input bias
    float* __restrict__ mx)            // [M, 192]
{
    const int tid  = threadIdx.x;
    const int l    = tid & 63;
    const int wv   = tid >> 6;          // 0..3
    const int lrow = l & 15;
    const int g    = l >> 4;            // 0..3 (k-group)
    const int m0   = blockIdx.x * 64;

    f32x4 acc[4][3];
#pragma unroll
    for (int ni = 0; ni < 3; ++ni) {
        const float b = bias[wv * 48 + ni * 16 + lrow];
        const f32x4 bv = {b, b, b, b};
#pragma unroll
        for (int mi = 0; mi < 4; ++mi) acc[mi][ni] = bv;
    }

    for (int ks = 0; ks < KSTEPS; ++ks) {
        f16x8 bhi[3], blo[3];
#pragma unroll
        for (int ni = 0; ni < 3; ++ni) {
            const size_t off = ((size_t)(ks * NTILES + wv * 3 + ni) * 64 + l) * 8;
            bhi[ni] = *(const f16x8*)(wt_hi + off);
            blo[ni] = *(const f16x8*)(wt_lo + off);
        }
#pragma unroll
        for (int mi = 0; mi < 4; ++mi) {
            const float* xr = x + (size_t)(m0 + mi * 16 + lrow) * D_ + ks * 32 + g * 8;
            float xv[8];
            if (ks < 9) {
                const float4 v0 = ((const float4*)xr)[0];
                const float4 v1 = ((const float4*)xr)[1];
                xv[0] = v0.x; xv[1] = v0.y; xv[2] = v0.z; xv[3] = v0.w;
                xv[4] = v1.x; xv[5] = v1.y; xv[6] = v1.z; xv[7] = v1.w;
            } else {
                const int kb = 288 + g * 8;   // predicated tail (k in [288,320))
#pragma unroll
                for (int e = 0; e < 8; ++e) xv[e] = (kb + e < D_) ? xr[e] : 0.f;
            }
            f16x8 ahi, alo;
#pragma unroll
            for (int e = 0; e < 8; ++e) {
                const half_t h = (half_t)xv[e];
                ahi[e] = h;
                alo[e] = (half_t)(xv[e] - (float)h);
            }
#pragma unroll
            for (int ni = 0; ni < 3; ++ni) {
                acc[mi][ni] = __builtin_amdgcn_mfma_f32_16x16x32_f16(ahi, bhi[ni], acc[mi][ni], 0, 0, 0);
                acc[mi][ni] = __builtin_amdgcn_mfma_f32_16x16x32_f16(alo, bhi[ni], acc[mi][ni], 0, 0, 0);
                acc[mi][ni] = __builtin_amdgcn_mfma_f32_16x16x32_f16(ahi, blo[ni], acc[mi][ni], 0, 0, 0);
            }
        }
    }

#pragma unroll
    for (int mi = 0; mi < 4; ++mi) {
        const int rbase = m0 + mi * 16 + g * 4;
#pragma unroll
        for (int ni = 0; ni < 3; ++ni) {
            const int col = wv * 48 + ni * 16 + lrow;
#pragma unroll
            for (int r = 0; r < 4; ++r)
                mx[(size_t)(rbase + r) * 192 + col] = acc[mi][ni][r];
        }
    }
}

// ---------------------------------------------------------------------------
// Kernel 2: GRU scan — 1 wave per batch element, zero barriers, f16 dot2.
// Lane j owns gate columns (j, 64+j, 128+j); R packed as f16x2 (96 VGPRs).
// h broadcast via 128 B LDS (f16): 1 ds_write_b16 + 8 uniform ds_read_b128
// per step. hn/hs stay fp32. mx prefetched with REAL depth 4 (unroll-4,
// statically indexed slots; load issued ~4 steps before consumption).
// ---------------------------------------------------------------------------
__global__ __launch_bounds__(64) void scan_kernel(
    const float* __restrict__ mx,    // [B, T, 192]
    const float* __restrict__ rk,    // [64, 192]
    const float* __restrict__ bias,  // [2, 192], row 1 = recurrent bias
    float* __restrict__ hs)          // [B, T, 64]
{
    __shared__ _Float16 hbuf[64];    // 128 B
    const int j = threadIdx.x;       // 0..63
    const int b = blockIdx.x;

    // recurrent kernel columns j / 64+j / 128+j as packed f16 pairs (u,u+1)
    f16x2 Rz[32], Rr[32], Rh[32];
#pragma unroll
    for (int p = 0; p < 32; ++p) {
        Rz[p] = f16x2{(_Float16)rk[(size_t)(2 * p) * 192 + j],
                      (_Float16)rk[(size_t)(2 * p + 1) * 192 + j]};
        Rr[p] = f16x2{(_Float16)rk[(size_t)(2 * p) * 192 + 64 + j],
                      (_Float16)rk[(size_t)(2 * p + 1) * 192 + 64 + j]};
        Rh[p] = f16x2{(_Float16)rk[(size_t)(2 * p) * 192 + 128 + j],
                      (_Float16)rk[(size_t)(2 * p + 1) * 192 + 128 + j]};
    }
    const float rbz = bias[192 + j];
    const float rbr = bias[192 + 64 + j];
    const float rbh = bias[192 + 128 + j];

    hbuf[j] = (_Float16)0.f;
    float hj = 0.f;

    const float* mxb = mx + (size_t)b * T_ * 192 + j;
    float* hsb = hs + (size_t)b * T_ * 64 + j;

    // prefetch slots, depth 4 (statically indexed via the unrolled loop)
    float zb[4], rbv[4], qb[4];
#pragma unroll
    for (int i = 0; i < 4; ++i) {
        const float* p = mxb + (size_t)i * 192;
        zb[i] = p[0]; rbv[i] = p[64]; qb[i] = p[128];
    }

    union H8 { f16x8 v; f16x2 p[4]; };

    for (int t0 = 0; t0 < T_; t0 += 4) {
#pragma unroll
        for (int i = 0; i < 4; ++i) {
            const int t = t0 + i;
            const float xz = zb[i], xr = rbv[i], xh = qb[i];

            // issue prefetch for t+4 immediately (consumed 4 steps later)
            {
                const int tp = (t + 4 < T_) ? (t + 4) : (T_ - 1);
                const float* pf = mxb + (size_t)tp * 192;
                zb[i] = pf[0]; rbv[i] = pf[64]; qb[i] = pf[128];
            }

            // read h broadcast: 8 uniform ds_read_b128 (64 f16 = 128 B)
            H8 hv[8];
            const f16x8* h8 = (const f16x8*)hbuf;
#pragma unroll
            for (int q = 0; q < 8; ++q) hv[q].v = h8[q];

            float az[4] = {rbz, 0.f, 0.f, 0.f};
            float ar[4] = {rbr, 0.f, 0.f, 0.f};
            float ah[4] = {rbh, 0.f, 0.f, 0.f};
#pragma unroll
            for (int p = 0; p < 32; ++p) {
                const f16x2 hp = hv[p >> 2].p[p & 3];
                az[p & 3] = fdot2_(hp, Rz[p], az[p & 3]);
                ar[p & 3] = fdot2_(hp, Rr[p], ar[p & 3]);
                ah[p & 3] = fdot2_(hp, Rh[p], ah[p & 3]);
            }
            const float miz = (az[0] + az[1]) + (az[2] + az[3]);
            const float mir = (ar[0] + ar[1]) + (ar[2] + ar[3]);
            const float mih = (ah[0] + ah[1]) + (ah[2] + ah[3]);

            const float zg = FRCP(1.f + __expf(-(xz + miz)));   // update gate
            const float rg = FRCP(1.f + __expf(-(xr + mir)));   // reset gate
            const float hh = fmaxf(fmaf(rg, mih, xh), 0.f);     // relu candidate
            const float hn = fmaf(zg, hj - hh, hh);             // z*h + (1-z)*hh

            hbuf[j] = (_Float16)hn;     // f16 broadcast for next step
            hj = hn;
            hsb[(size_t)t * 64] = hn;   // fp32 history for the head
        }
    }
}

// ---------------------------------------------------------------------------
// Kernel 3: logits + softmax. hrow is wave-private -> no barriers needed.
// ---------------------------------------------------------------------------
__global__ __launch_bounds__(256) void head_kernel(
    const float* __restrict__ hs,   // [M, 64]
    const float* __restrict__ dw,   // [64, 45]
    const float* __restrict__ db,   // [45]
    float* __restrict__ out)        // [M, 45]
{
    __shared__ float hrow[4][64];
    const int lane = threadIdx.x & 63;
    const int wv   = threadIdx.x >> 6;

    float Wreg[64];
    float bj = 0.f;
    if (lane < C_) {
        bj = db[lane];
#pragma unroll
        for (int u = 0; u < 64; ++u) Wreg[u] = dw[u * C_ + lane];
    } else {
#pragma unroll
        for (int u = 0; u < 64; ++u) Wreg[u] = 0.f;
    }

    const int gw = blockIdx.x * 4 + wv;
    const int nw = gridDim.x * 4;
    const int M  = B_ * T_;
    for (int row = gw; row < M; row += nw) {
        const float h = hs[(size_t)row * 64 + lane];
        hrow[wv][lane] = h;   // wave-private slice; in-wave DS ordering suffices

        float acc = bj;
        const float4* h4 = (const float4*)hrow[wv];
#pragma unroll
        for (int g = 0; g < 16; ++g) {
            const float4 hv = h4[g];
            acc = fmaf(hv.x, Wreg[4 * g + 0], acc);
            acc = fmaf(hv.y, Wreg[4 * g + 1], acc);
            acc = fmaf(hv.z, Wreg[4 * g + 2], acc);
            acc = fmaf(hv.w, Wreg[4 * g + 3], acc);
        }

        float lg = (lane < C_) ? acc : -INFINITY;
        float mxv = lg;
#pragma unroll
        for (int s = 32; s; s >>= 1) mxv = fmaxf(mxv, __shfl_xor(mxv, s, 64));
        const float e = (lane < C_) ? __expf(lg - mxv) : 0.f;
        float ssum = e;
#pragma unroll
        for (int s = 32; s; s >>= 1) ssum += __shfl_xor(ssum, s, 64);
        if (lane < C_) out[(size_t)row * C_ + lane] = e / ssum;
    }
}

// ---------------------------------------------------------------------------
extern "C" void kernel_launch(void* const* d_in, const int* in_sizes, int n_in,
                              void* d_out, int out_size, void* d_ws, size_t ws_size,
                              hipStream_t stream) {
    const float* x  = (const float*)d_in[0];
    const float* w  = (const float*)d_in[1];
    const float* rk = (const float*)d_in[2];
    const float* bs = (const float*)d_in[3];
    const float* dw = (const float*)d_in[4];
    const float* db = (const float*)d_in[5];
    float* out = (float*)d_out;

    char* ws = (char*)d_ws;
    float*  mx    = (float*)ws;                                  // 100.66 MB
    float*  hs    = (float*)(ws + (size_t)131072 * 192 * 4);     //  33.55 MB
    half_t* wt_hi = (half_t*)(ws + (size_t)131072 * 256 * 4);    // 122,880 B
    half_t* wt_lo = wt_hi + (size_t)KSTEPS * NTILES * 64 * 8;    // 122,880 B

    prep_kernel<<<30,   256, 0, stream>>>(w, wt_hi, wt_lo);
    proj_kernel<<<2048, 256, 0, stream>>>(x, wt_hi, wt_lo, bs, mx);
    scan_kernel<<<256,  64,  0, stream>>>(mx, rk, bs, hs);
    head_kernel<<<2048, 256, 0, stream>>>(hs, dw, db, out);
}